// Round 3
// baseline (359.307 us; speedup 1.0000x reference)
//
#include <hip/hip_runtime.h>
#include <hip/hip_bf16.h>
#include <math.h>

#define H    128
#define NB   4      // batch
#define NSEG 200    // segments
#define NS   512    // tokens per segment
#define GN   10     // n-rows per weighted-kernel block
#define GS   32     // s-rows per weighted-kernel block
#define NGRP (NSEG / GN)   // 20 token-partial groups
#define NST  (NS / GS)     // 16 result-partial s-tiles

// ---------------------------------------------------------------------------
// ws layout (floats):
//   w     : [0, 409600)                        B*N*S softmax weights
//   rpart : [409600, 2048000)                  B*N*NST*H result partials
//   tpart : [2048000, 7290880)                 NGRP*B*S*H token partials
// ---------------------------------------------------------------------------

// Kernel 1: per-(b,n) segment. Inline q/v/c0 precompute (redundant per block,
// trivial), then coalesced dot-scores via shfl, mask, softmax, write w.
__global__ __launch_bounds__(512)
void scores_softmax_kernel(const float* __restrict__ context,
                           const float* __restrict__ mask,
                           const float* __restrict__ query,
                           const float* __restrict__ Wq,
                           const float* __restrict__ bq,
                           const float* __restrict__ Wc,
                           const float* __restrict__ bc,
                           float* __restrict__ w_out) {
    __shared__ float  qsh[H];
    __shared__ float4 vv4[32];
    __shared__ float  mk[NS];
    __shared__ float  sc[NS];
    __shared__ float  wred[8];
    __shared__ float  c0sh;

    const int tid = threadIdx.x;       // 0..511
    const int blk = blockIdx.x;        // b*NSEG + n
    const int b   = blk / NSEG;
    const float* cseg = context + (size_t)blk * NS * H;

    // ---- inline precompute: q = query@Wq.T + bq ; v = q@Wc ; c0 = q.bc ----
    if (tid < H) {
        float acc = bq[tid];
        const float* qr = query + b * H;
        const float* wr = Wq + tid * H;
        #pragma unroll 4
        for (int k = 0; k < H; ++k) acc += qr[k] * wr[k];
        qsh[tid] = acc;
    }
    mk[tid] = mask[(size_t)blk * NS + tid];
    __syncthreads();
    if (tid < H) {
        float vacc = 0.f;
        #pragma unroll 4
        for (int h2 = 0; h2 < H; ++h2) vacc += qsh[h2] * Wc[h2 * H + tid];
        ((float*)vv4)[tid] = vacc;
    }
    if (tid < 64) {
        float p = qsh[tid] * bc[tid] + qsh[tid + 64] * bc[tid + 64];
        for (int o = 32; o > 0; o >>= 1) p += __shfl_xor(p, o);
        if (tid == 0) c0sh = p;
    }
    __syncthreads();

    const int   h4  = tid & 31;        // float4 chunk within row
    const int   rg  = tid >> 5;        // 0..15 rows in flight
    const float c0b = c0sh;

    // ---- scores: 32 lanes per row, wave load = 1 KB contiguous ----
    #pragma unroll 4
    for (int it = 0; it < NS / 16; ++it) {
        const int s = it * 16 + rg;
        const float4 cv = ((const float4*)(cseg + (size_t)s * H))[h4];
        const float4 vq = vv4[h4];
        float p = cv.x * vq.x + cv.y * vq.y + cv.z * vq.z + cv.w * vq.w;
        p += __shfl_xor(p, 16);
        p += __shfl_xor(p, 8);
        p += __shfl_xor(p, 4);
        p += __shfl_xor(p, 2);
        p += __shfl_xor(p, 1);
        if (h4 == 0) sc[s] = (p + c0b) * mk[s];
    }
    __syncthreads();

    // ---- softmax over 512 elements, one per thread ----
    const float x = sc[tid];
    float m = x;
    for (int o = 32; o > 0; o >>= 1) m = fmaxf(m, __shfl_xor(m, o));
    const int wid = tid >> 6, lane = tid & 63;
    if (lane == 0) wred[wid] = m;
    __syncthreads();
    if (tid == 0) {
        float mm = wred[0];
        for (int i = 1; i < 8; ++i) mm = fmaxf(mm, wred[i]);
        wred[0] = mm;
    }
    __syncthreads();
    const float mx = wred[0];
    const float e  = __expf(x - mx);
    float ssum = e;
    for (int o = 32; o > 0; o >>= 1) ssum += __shfl_xor(ssum, o);
    __syncthreads();
    if (lane == 0) wred[wid] = ssum;
    __syncthreads();
    if (tid == 0) {
        float t = 0.f;
        for (int i = 0; i < 8; ++i) t += wred[i];
        wred[0] = t;
    }
    __syncthreads();
    w_out[(size_t)blk * NS + tid] = e / wred[0];
}

// Kernel 2: ONE coalesced (L3-hot) read of context -> partials for BOTH
// outputs. Block owns (b, 10 n-rows, 32 s-rows), 256 threads.
__global__ __launch_bounds__(256)
void weighted_kernel(const float* __restrict__ context,
                     const float* __restrict__ w,
                     float* __restrict__ result_part,
                     float* __restrict__ token_part) {
    const int bid = blockIdx.x;            // ((b*NGRP + ng)*NST + st)
    const int st  = bid & (NST - 1);
    const int tmp = bid / NST;
    const int ng  = tmp % NGRP;
    const int b   = tmp / NGRP;
    const int n0  = ng * GN;
    const int s0  = st * GS;

    const int tid = threadIdx.x;
    const int h4  = tid & 31;              // float4 chunk within row
    const int rg  = tid >> 5;              // 0..7 s-subgroup

    __shared__ float  wt[GN * GS];         // 1.25 KB
    __shared__ float4 red4[5 * 8 * 32];    // 20 KB

    for (int i = tid; i < GN * GS; i += 256) {
        const int nn = i >> 5, ss = i & (GS - 1);
        wt[i] = w[((size_t)(b * NSEG + n0 + nn)) * NS + s0 + ss];
    }
    __syncthreads();

    float4 racc[GN];
    float4 tacc[4];
    #pragma unroll
    for (int n = 0; n < GN; ++n) racc[n] = make_float4(0.f, 0.f, 0.f, 0.f);
    #pragma unroll
    for (int j = 0; j < 4; ++j) tacc[j] = make_float4(0.f, 0.f, 0.f, 0.f);

    #pragma unroll
    for (int n = 0; n < GN; ++n) {
        const float* base = context + ((size_t)(b * NSEG + n0 + n) * NS + s0) * (size_t)H;
        #pragma unroll
        for (int j = 0; j < 4; ++j) {
            const int s = j * 8 + rg;
            const float  wv = wt[n * GS + s];
            const float4 cv = ((const float4*)(base + (size_t)s * H))[h4];
            racc[n].x += wv * cv.x; racc[n].y += wv * cv.y;
            racc[n].z += wv * cv.z; racc[n].w += wv * cv.w;
            tacc[j].x += wv * cv.x; tacc[j].y += wv * cv.y;
            tacc[j].z += wv * cv.z; tacc[j].w += wv * cv.w;
        }
    }

    // token partial: [ng][b][s][h], each row owned by exactly one block
    #pragma unroll
    for (int j = 0; j < 4; ++j) {
        const int s = j * 8 + rg;
        ((float4*)token_part)[(((size_t)ng * NB + b) * NS + s0 + s) * 32 + h4] = tacc[j];
    }

    // result partial: reduce racc over 8 rg-groups, batched 5 n per round
    for (int nb = 0; nb < GN; nb += 5) {
        #pragma unroll
        for (int j = 0; j < 5; ++j)
            red4[(j * 8 + rg) * 32 + h4] = racc[nb + j];
        __syncthreads();
        for (int off = 4; off > 0; off >>= 1) {
            if (rg < off) {
                #pragma unroll
                for (int j = 0; j < 5; ++j) {
                    float4 o = red4[(j * 8 + rg + off) * 32 + h4];
                    float4 mm = red4[(j * 8 + rg) * 32 + h4];
                    mm.x += o.x; mm.y += o.y; mm.z += o.z; mm.w += o.w;
                    red4[(j * 8 + rg) * 32 + h4] = mm;
                }
            }
            __syncthreads();
        }
        if (rg == 0) {
            #pragma unroll
            for (int j = 0; j < 5; ++j)
                ((float4*)result_part)[(((size_t)(b * NSEG + n0 + nb + j)) * NST + st) * 32 + h4]
                    = red4[(j * 8) * 32 + h4];
        }
        __syncthreads();
    }
}

// Kernel 3: both combines in one launch.
//   i < RQ  : result[b,n,h] = sum over NST s-tiles
//   i >= RQ : token_result[b,s,h] = sum over NGRP n-groups
__global__ __launch_bounds__(256)
void combine_kernel(const float* __restrict__ rpart,
                    const float* __restrict__ tpart,
                    float* __restrict__ out) {
    const int RQ = NB * NSEG * H / 4;                      // 25600 float4
    const int i  = blockIdx.x * 256 + threadIdx.x;
    if (i < RQ) {
        const int row = i >> 5, h4 = i & 31;
        float4 acc = {0.f, 0.f, 0.f, 0.f};
        const float4* p = (const float4*)rpart;
        #pragma unroll
        for (int st = 0; st < NST; ++st) {
            float4 o = p[((size_t)row * NST + st) * 32 + h4];
            acc.x += o.x; acc.y += o.y; acc.z += o.z; acc.w += o.w;
        }
        ((float4*)out)[i] = acc;
    } else {
        const int j = i - RQ;                              // 0..65535
        float4 acc = {0.f, 0.f, 0.f, 0.f};
        const float4* p = (const float4*)tpart;
        #pragma unroll
        for (int g = 0; g < NGRP; ++g) {
            float4 o = p[(size_t)g * (NB * NS * H / 4) + j];
            acc.x += o.x; acc.y += o.y; acc.z += o.z; acc.w += o.w;
        }
        ((float4*)out)[i] = acc;
    }
}

extern "C" void kernel_launch(void* const* d_in, const int* in_sizes, int n_in,
                              void* d_out, int out_size, void* d_ws, size_t ws_size,
                              hipStream_t stream) {
    const float* query   = (const float*)d_in[0];
    const float* context = (const float*)d_in[1];
    const float* mask    = (const float*)d_in[2];
    const float* Wq      = (const float*)d_in[3];
    const float* bq      = (const float*)d_in[4];
    const float* Wc      = (const float*)d_in[5];
    const float* bc      = (const float*)d_in[6];

    float* out = (float*)d_out;
    float* wsf = (float*)d_ws;

    float* w     = wsf;                                   // B*N*S
    float* rpart = wsf + NB * NSEG * NS;                  // B*N*NST*H
    float* tpart = rpart + NB * NSEG * NST * H;           // NGRP*B*S*H

    scores_softmax_kernel<<<NB * NSEG, 512, 0, stream>>>(
        context, mask, query, Wq, bq, Wc, bc, w);
    weighted_kernel<<<NB * NGRP * NST, 256, 0, stream>>>(context, w, rpart, tpart);
    const int total4 = NB * NSEG * H / 4 + NB * NS * H / 4;   // 91136
    combine_kernel<<<total4 / 256, 256, 0, stream>>>(rpart, tpart, out);
}